// Round 4
// baseline (611.928 us; speedup 1.0000x reference)
//
#include <hip/hip_runtime.h>
#include <math.h>

// Problem constants
#define NP 8836          // number of patches per image (94*94)
#define PW 94            // patches per row
#define IW 96            // image width/height
#define CH 256           // channels
#define NTILE 70         // ceil(8836/128)
#define KT 36            // K tiles: 2304/64

typedef int   i32x8  __attribute__((ext_vector_type(8)));
typedef float f32x16 __attribute__((ext_vector_type(16)));

__device__ __forceinline__ unsigned int ordf(float f) {
  unsigned int u = __float_as_uint(f);
  return (u & 0x80000000u) ? ~u : (u | 0x80000000u);
}

typedef const __attribute__((address_space(1))) void GvoidC;
typedef __attribute__((address_space(3))) void Lvoid;
__device__ __forceinline__ void gl16(const void* g, void* l) {
  __builtin_amdgcn_global_load_lds((GvoidC*)g, (Lvoid*)l, 16, 0, 0);
}

// ---------------------------------------------------------------------------
// 1) Convert+transpose [C, 9216] fp32 -> [9216, C] fp8 (HW v_cvt encoding).
//    LDS tile transpose 64xy x 64c; reads coalesced (xy), writes packed u32
//    (4 c per thread) coalesced along c.
// ---------------------------------------------------------------------------
__global__ __launch_bounds__(256) void prep_kernel(
    const float* __restrict__ inA, const float* __restrict__ inB,
    unsigned int* __restrict__ TA, unsigned int* __restrict__ TB) {
  __shared__ float tile[64][65];
  int bid = blockIdx.x;            // [0, 1152)
  const float* src; unsigned int* dst;
  if (bid < 576) { src = inA; dst = TA; }
  else           { src = inB; dst = TB; bid -= 576; }
  int cT  = bid & 3;        // c-tile   [0,4)  (64 channels)
  int xyT = bid >> 2;       // xy-tile  [0,144)
  int t = threadIdx.x;
  int l = t & 63, h = t >> 6;

  #pragma unroll
  for (int i = 0; i < 16; ++i) {
    int c = h * 16 + i;
    tile[c][l] = src[(size_t)(cT * 64 + c) * (IW * IW) + xyT * 64 + l];
  }
  __syncthreads();
  int cu = t & 15;          // u32 column within the 64-channel tile
  #pragma unroll
  for (int i = 0; i < 4; ++i) {
    int xy = (t >> 4) + i * 16;
    int c = cu * 4;
    unsigned int v = __builtin_amdgcn_cvt_pk_fp8_f32(tile[c][xy],     tile[c + 1][xy], 0, false);
    v              = __builtin_amdgcn_cvt_pk_fp8_f32(tile[c + 2][xy], tile[c + 3][xy], v, true);
    dst[(size_t)(xyT * 64 + xy) * 64 + cT * 16 + cu] = v;
  }
}

// ---------------------------------------------------------------------------
// 2) Per-patch squared norms from the fp8 images (consistent with GEMM dtype).
//    One wave per patch: 9 x 64 u32 reads, decode 4 fp8 each (selectors must
//    be literal constants for __builtin_amdgcn_cvt_f32_fp8).
// ---------------------------------------------------------------------------
__global__ void norms_kernel(const unsigned int* __restrict__ TA, const unsigned int* __restrict__ TB,
                             float* __restrict__ rnormS, float* __restrict__ normS,
                             float* __restrict__ normsqS, float* __restrict__ synsq) {
  int wid  = blockIdx.x * 4 + (threadIdx.x >> 6);
  int lane = threadIdx.x & 63;
  bool isStyle = wid < NP;
  int p = isStyle ? wid : wid - NP;
  if (p >= NP) return;
  const unsigned int* T = isStyle ? TB : TA;
  int pi = p / PW, pj = p % PW;
  float s = 0.f;
  #pragma unroll
  for (int kh = 0; kh < 3; ++kh) {
    #pragma unroll
    for (int kw = 0; kw < 3; ++kw) {
      unsigned int v = T[(size_t)((pi + kh) * IW + (pj + kw)) * 64 + lane];
      float f0 = __builtin_amdgcn_cvt_f32_fp8(v, 0);
      float f1 = __builtin_amdgcn_cvt_f32_fp8(v, 1);
      float f2 = __builtin_amdgcn_cvt_f32_fp8(v, 2);
      float f3 = __builtin_amdgcn_cvt_f32_fp8(v, 3);
      s += f0 * f0 + f1 * f1 + f2 * f2 + f3 * f3;
    }
  }
  #pragma unroll
  for (int m = 32; m >= 1; m >>= 1) s += __shfl_xor(s, m, 64);
  if (lane == 0) {
    if (isStyle) {
      normsqS[p] = s;
      float n = sqrtf(s);
      normS[p]  = n;
      rnormS[p] = 1.f / n;
    } else {
      synsq[p] = s;
    }
  }
}

// ---------------------------------------------------------------------------
// 3) MX-fp8 implicit-im2col GEMM (Q x S x 2304) with fused argmax epilogue.
//    128x128 tile, BK=64, 4 waves (2x2, each 64x64 = 2x2 blocks of 32x32),
//    mfma_scale_f32_32x32x64_f8f6f4 with unit scales (e8m0 = 0x7F).
//    A-frag: lane holds A[m=lane&31][k=(lane>>5)*32 + j], j in [0,32) —
//    32 contiguous bytes -> 2x ds_read_b128.
// ---------------------------------------------------------------------------
__global__ __launch_bounds__(256) void gemm_argmax_kernel(
    const unsigned char* __restrict__ TA, const unsigned char* __restrict__ TB,
    const float* __restrict__ rnormS, unsigned long long* __restrict__ best) {
  __shared__ unsigned char As[128 * 64];
  __shared__ unsigned char Bs[128 * 64];

  int pid = blockIdx.x;
  int mt = pid % NTILE, nt = pid / NTILE;
  int q0 = mt * 128, s0 = nt * 128;
  int t = threadIdx.x, lane = t & 63, wave = t >> 6;
  int wm = wave >> 1, wn = wave & 1;

  // Staging: thread t covers rows r=t>>2 and r+64; 16B chunk cs=t&3 of the
  // 64B k-piece. LDS dest contiguous (required by global_load_lds).
  int r = t >> 2, cs = t & 3;
  int qa0 = q0 + r;      if (qa0 > NP - 1) qa0 = NP - 1;
  int qa1 = q0 + r + 64; if (qa1 > NP - 1) qa1 = NP - 1;
  int sa0 = s0 + r;      if (sa0 > NP - 1) sa0 = NP - 1;
  int sa1 = s0 + r + 64; if (sa1 > NP - 1) sa1 = NP - 1;
  const unsigned char* gA0 = TA + (size_t)((qa0 / PW) * IW + (qa0 % PW)) * CH + cs * 16;
  const unsigned char* gA1 = TA + (size_t)((qa1 / PW) * IW + (qa1 % PW)) * CH + cs * 16;
  const unsigned char* gB0 = TB + (size_t)((sa0 / PW) * IW + (sa0 % PW)) * CH + cs * 16;
  const unsigned char* gB1 = TB + (size_t)((sa1 / PW) * IW + (sa1 % PW)) * CH + cs * 16;
  unsigned char* lA0 = As + t * 16;
  unsigned char* lA1 = lA0 + 4096;
  unsigned char* lB0 = Bs + t * 16;
  unsigned char* lB1 = lB0 + 4096;

  f32x16 acc[2][2];
  #pragma unroll
  for (int mi = 0; mi < 2; ++mi)
    #pragma unroll
    for (int ni = 0; ni < 2; ++ni)
      #pragma unroll
      for (int j = 0; j < 16; ++j)
        acc[mi][ni][j] = 0.f;

  const unsigned char* Ap = As + (size_t)(wm * 64 + (lane & 31)) * 64 + (lane >> 5) * 32;
  const unsigned char* Bp = Bs + (size_t)(wn * 64 + (lane & 31)) * 64 + (lane >> 5) * 32;

  for (int kt = 0; kt < KT; ++kt) {
    int chunk = kt >> 2;                 // which (kh,kw) of 9
    int kh = chunk / 3, kw = chunk - kh * 3;
    int choff = (kh * IW + kw) * CH + (kt & 3) * 64;   // bytes
    if (kt) __syncthreads();
    gl16(gA0 + choff, lA0);
    gl16(gA1 + choff, lA1);
    gl16(gB0 + choff, lB0);
    gl16(gB1 + choff, lB1);
    __syncthreads();

    i32x8 af[2], bf[2];
    #pragma unroll
    for (int mi = 0; mi < 2; ++mi) af[mi] = *(const i32x8*)(Ap + mi * 32 * 64);
    #pragma unroll
    for (int ni = 0; ni < 2; ++ni) bf[ni] = *(const i32x8*)(Bp + ni * 32 * 64);
    #pragma unroll
    for (int mi = 0; mi < 2; ++mi)
      #pragma unroll
      for (int ni = 0; ni < 2; ++ni)
        acc[mi][ni] = __builtin_amdgcn_mfma_scale_f32_32x32x64_f8f6f4(
            af[mi], bf[ni], acc[mi][ni],
            0, 0,                       // A fmt = fp8(e4m3), B fmt = fp8
            0, 0x7F7F7F7F,              // opsel_a, scale_a = 1.0 (e8m0 127)
            0, 0x7F7F7F7F);             // opsel_b, scale_b = 1.0
  }

  // Epilogue. C/D layout (32x32): col = lane&31, row = (reg&3)+8*(reg>>2)+4*(lane>>5).
  int col = lane & 31, half = lane >> 5;
  float rn[2]; int sc[2]; bool sv[2];
  #pragma unroll
  for (int ni = 0; ni < 2; ++ni) {
    int s = s0 + wn * 64 + ni * 32 + col;
    sc[ni] = s;
    sv[ni] = (s < NP);
    rn[ni] = sv[ni] ? rnormS[s] : 0.f;
  }
  #pragma unroll
  for (int mi = 0; mi < 2; ++mi) {
    #pragma unroll
    for (int reg = 0; reg < 16; ++reg) {
      unsigned long long p = 0ull;
      #pragma unroll
      for (int ni = 0; ni < 2; ++ni) {
        float v = acc[mi][ni][reg] * rn[ni];
        unsigned long long cand =
            ((unsigned long long)ordf(v) << 32) |
            (unsigned long long)(0xFFFFFFFFu - (unsigned)sc[ni]);
        cand = sv[ni] ? cand : 0ull;
        if (cand > p) p = cand;
      }
      #pragma unroll
      for (int sh = 16; sh >= 1; sh >>= 1) {   // reduce within each 32-lane half
        unsigned long long o = __shfl_xor(p, sh, 64);
        if (o > p) p = o;
      }
      int q = q0 + wm * 64 + mi * 32 + (reg & 3) + 8 * (reg >> 2) + 4 * half;
      if (col == 0 && q < NP) atomicMax(best + q, p);
    }
  }
}

// ---------------------------------------------------------------------------
// 4) Final loss: loss = mean_q (synsq[q] - 2*dot + normsq[nn]) / 2304
// ---------------------------------------------------------------------------
__global__ void finalize_kernel(const unsigned long long* __restrict__ best,
                                const float* __restrict__ normS,
                                const float* __restrict__ normsqS,
                                const float* __restrict__ synsq,
                                float* __restrict__ out) {
  __shared__ float sm[256];
  int t = threadIdx.x;
  float accum = 0.f;
  for (int q = t; q < NP; q += 256) {
    unsigned long long p = best[q];
    unsigned int o   = (unsigned int)(p >> 32);
    unsigned int idx = 0xFFFFFFFFu - (unsigned int)(p & 0xFFFFFFFFull);
    unsigned int u   = (o & 0x80000000u) ? (o & 0x7FFFFFFFu) : ~o;
    float resp = __uint_as_float(u);
    float dot  = resp * normS[idx];
    accum += synsq[q] - 2.f * dot + normsqS[idx];
  }
  sm[t] = accum;
  __syncthreads();
  for (int s = 128; s >= 1; s >>= 1) {
    if (t < s) sm[t] += sm[t + s];
    __syncthreads();
  }
  if (t == 0) out[0] = sm[0] / ((float)NP * 2304.f);
}

// ---------------------------------------------------------------------------
extern "C" void kernel_launch(void* const* d_in, const int* in_sizes, int n_in,
                              void* d_out, int out_size, void* d_ws, size_t ws_size,
                              hipStream_t stream) {
  const float* inA = (const float*)d_in[0];  // input  (synthesis)
  const float* inB = (const float*)d_in[1];  // target (style)
  float* out = (float*)d_out;

  char* ws = (char*)d_ws;
  unsigned char* TA = (unsigned char*)ws;                 // 2,359,296 B fp8
  unsigned char* TB = (unsigned char*)(ws + 2359296);     // 2,359,296 B fp8
  float* rnormS  = (float*)(ws + 4718592);
  float* normS   = (float*)(ws + 4718592 + 35344);
  float* normsqS = (float*)(ws + 4718592 + 70688);
  float* synsq   = (float*)(ws + 4718592 + 106032);
  unsigned long long* best = (unsigned long long*)(ws + 4718592 + 141376);

  (void)hipMemsetAsync(best, 0, (size_t)NP * 8, stream);
  prep_kernel<<<dim3(1152), dim3(256), 0, stream>>>(inA, inB, (unsigned int*)TA, (unsigned int*)TB);
  norms_kernel<<<dim3((2 * NP + 3) / 4), dim3(256), 0, stream>>>(
      (const unsigned int*)TA, (const unsigned int*)TB, rnormS, normS, normsqS, synsq);
  gemm_argmax_kernel<<<dim3(NTILE * NTILE), dim3(256), 0, stream>>>(TA, TB, rnormS, best);
  finalize_kernel<<<dim3(1), dim3(256), 0, stream>>>(best, normS, normsqS, synsq, out);
}

// Round 5
// 368.958 us; speedup vs baseline: 1.6585x; 1.6585x over previous
//
#include <hip/hip_runtime.h>
#include <math.h>

// Problem constants
#define NP 8836          // number of patches per image (94*94)
#define PW 94            // patches per row
#define IW 96            // image width/height
#define CH 256           // channels
#define NTILE 70         // ceil(8836/128)
#define KT 36            // K tiles: 2304/64

typedef int   i32x8  __attribute__((ext_vector_type(8)));
typedef float f32x16 __attribute__((ext_vector_type(16)));

__device__ __forceinline__ unsigned int ordf(float f) {
  unsigned int u = __float_as_uint(f);
  return (u & 0x80000000u) ? ~u : (u | 0x80000000u);
}

typedef const __attribute__((address_space(1))) void GvoidC;
typedef __attribute__((address_space(3))) void Lvoid;
__device__ __forceinline__ void gl16(const void* g, void* l) {
  __builtin_amdgcn_global_load_lds((GvoidC*)g, (Lvoid*)l, 16, 0, 0);
}

// ---------------------------------------------------------------------------
// 1) Convert+transpose [C, 9216] fp32 -> [9216, C] fp8 (HW v_cvt encoding).
// ---------------------------------------------------------------------------
__global__ __launch_bounds__(256) void prep_kernel(
    const float* __restrict__ inA, const float* __restrict__ inB,
    unsigned int* __restrict__ TA, unsigned int* __restrict__ TB) {
  __shared__ float tile[64][65];
  int bid = blockIdx.x;            // [0, 1152)
  const float* src; unsigned int* dst;
  if (bid < 576) { src = inA; dst = TA; }
  else           { src = inB; dst = TB; bid -= 576; }
  int cT  = bid & 3;        // c-tile   [0,4)  (64 channels)
  int xyT = bid >> 2;       // xy-tile  [0,144)
  int t = threadIdx.x;
  int l = t & 63, h = t >> 6;

  #pragma unroll
  for (int i = 0; i < 16; ++i) {
    int c = h * 16 + i;
    tile[c][l] = src[(size_t)(cT * 64 + c) * (IW * IW) + xyT * 64 + l];
  }
  __syncthreads();
  int cu = t & 15;          // u32 column within the 64-channel tile
  #pragma unroll
  for (int i = 0; i < 4; ++i) {
    int xy = (t >> 4) + i * 16;
    int c = cu * 4;
    unsigned int v = __builtin_amdgcn_cvt_pk_fp8_f32(tile[c][xy],     tile[c + 1][xy], 0, false);
    v              = __builtin_amdgcn_cvt_pk_fp8_f32(tile[c + 2][xy], tile[c + 3][xy], v, true);
    dst[(size_t)(xyT * 64 + xy) * 64 + cT * 16 + cu] = v;
  }
}

// ---------------------------------------------------------------------------
// 2) Per-patch squared norms from the fp8 images (consistent with GEMM dtype).
// ---------------------------------------------------------------------------
__global__ void norms_kernel(const unsigned int* __restrict__ TA, const unsigned int* __restrict__ TB,
                             float* __restrict__ rnormS, float* __restrict__ normS,
                             float* __restrict__ normsqS, float* __restrict__ synsq) {
  int wid  = blockIdx.x * 4 + (threadIdx.x >> 6);
  int lane = threadIdx.x & 63;
  bool isStyle = wid < NP;
  int p = isStyle ? wid : wid - NP;
  if (p >= NP) return;
  const unsigned int* T = isStyle ? TB : TA;
  int pi = p / PW, pj = p % PW;
  float s = 0.f;
  #pragma unroll
  for (int kh = 0; kh < 3; ++kh) {
    #pragma unroll
    for (int kw = 0; kw < 3; ++kw) {
      unsigned int v = T[(size_t)((pi + kh) * IW + (pj + kw)) * 64 + lane];
      float f0 = __builtin_amdgcn_cvt_f32_fp8(v, 0);
      float f1 = __builtin_amdgcn_cvt_f32_fp8(v, 1);
      float f2 = __builtin_amdgcn_cvt_f32_fp8(v, 2);
      float f3 = __builtin_amdgcn_cvt_f32_fp8(v, 3);
      s += f0 * f0 + f1 * f1 + f2 * f2 + f3 * f3;
    }
  }
  #pragma unroll
  for (int m = 32; m >= 1; m >>= 1) s += __shfl_xor(s, m, 64);
  if (lane == 0) {
    if (isStyle) {
      normsqS[p] = s;
      float n = sqrtf(s);
      normS[p]  = n;
      rnormS[p] = 1.f / n;
    } else {
      synsq[p] = s;
    }
  }
}

// ---------------------------------------------------------------------------
// 3) MX-fp8 implicit-im2col GEMM (Q x S x 2304) with fused argmax epilogue.
//    128x128 tile, BK=64, mfma_scale_f32_32x32x64_f8f6f4, unit scales.
//    __launch_bounds__(256,2): cap unified VGPR+AGPR at 256/wave so 2
//    blocks/CU stay resident (round-4 regression: 244 VGPR -> 1 wave/SIMD,
//    MfmaUtil 13.6%). #pragma unroll 1 stops cross-iteration pipelining
//    from inflating live ranges.
// ---------------------------------------------------------------------------
__global__ __launch_bounds__(256, 2) void gemm_argmax_kernel(
    const unsigned char* __restrict__ TA, const unsigned char* __restrict__ TB,
    const float* __restrict__ rnormS, unsigned long long* __restrict__ best) {
  __shared__ unsigned char As[128 * 64];
  __shared__ unsigned char Bs[128 * 64];

  int pid = blockIdx.x;
  int mt = pid % NTILE, nt = pid / NTILE;
  int q0 = mt * 128, s0 = nt * 128;
  int t = threadIdx.x, lane = t & 63, wave = t >> 6;
  int wm = wave >> 1, wn = wave & 1;

  int r = t >> 2, cs = t & 3;
  int qa0 = q0 + r;      if (qa0 > NP - 1) qa0 = NP - 1;
  int qa1 = q0 + r + 64; if (qa1 > NP - 1) qa1 = NP - 1;
  int sa0 = s0 + r;      if (sa0 > NP - 1) sa0 = NP - 1;
  int sa1 = s0 + r + 64; if (sa1 > NP - 1) sa1 = NP - 1;
  const unsigned char* gA0 = TA + (size_t)((qa0 / PW) * IW + (qa0 % PW)) * CH + cs * 16;
  const unsigned char* gA1 = TA + (size_t)((qa1 / PW) * IW + (qa1 % PW)) * CH + cs * 16;
  const unsigned char* gB0 = TB + (size_t)((sa0 / PW) * IW + (sa0 % PW)) * CH + cs * 16;
  const unsigned char* gB1 = TB + (size_t)((sa1 / PW) * IW + (sa1 % PW)) * CH + cs * 16;
  unsigned char* lA0 = As + t * 16;
  unsigned char* lA1 = lA0 + 4096;
  unsigned char* lB0 = Bs + t * 16;
  unsigned char* lB1 = lB0 + 4096;

  f32x16 acc[2][2];
  #pragma unroll
  for (int mi = 0; mi < 2; ++mi)
    #pragma unroll
    for (int ni = 0; ni < 2; ++ni)
      #pragma unroll
      for (int j = 0; j < 16; ++j)
        acc[mi][ni][j] = 0.f;

  const unsigned char* Ap = As + (size_t)(wm * 64 + (lane & 31)) * 64 + (lane >> 5) * 32;
  const unsigned char* Bp = Bs + (size_t)(wn * 64 + (lane & 31)) * 64 + (lane >> 5) * 32;

  #pragma unroll 1
  for (int kt = 0; kt < KT; ++kt) {
    int chunk = kt >> 2;                 // which (kh,kw) of 9
    int kh = chunk / 3, kw = chunk - kh * 3;
    int choff = (kh * IW + kw) * CH + (kt & 3) * 64;   // bytes
    if (kt) __syncthreads();
    gl16(gA0 + choff, lA0);
    gl16(gA1 + choff, lA1);
    gl16(gB0 + choff, lB0);
    gl16(gB1 + choff, lB1);
    __syncthreads();

    i32x8 af[2], bf[2];
    #pragma unroll
    for (int mi = 0; mi < 2; ++mi) af[mi] = *(const i32x8*)(Ap + mi * 32 * 64);
    #pragma unroll
    for (int ni = 0; ni < 2; ++ni) bf[ni] = *(const i32x8*)(Bp + ni * 32 * 64);
    #pragma unroll
    for (int mi = 0; mi < 2; ++mi)
      #pragma unroll
      for (int ni = 0; ni < 2; ++ni)
        acc[mi][ni] = __builtin_amdgcn_mfma_scale_f32_32x32x64_f8f6f4(
            af[mi], bf[ni], acc[mi][ni],
            0, 0,                       // A fmt = fp8(e4m3), B fmt = fp8
            0, 0x7F7F7F7F,              // opsel_a, scale_a = 1.0 (e8m0 127)
            0, 0x7F7F7F7F);             // opsel_b, scale_b = 1.0
  }

  // Epilogue. C/D layout (32x32): col = lane&31, row = (reg&3)+8*(reg>>2)+4*(lane>>5).
  int col = lane & 31, half = lane >> 5;
  float rn[2]; int sc[2]; bool sv[2];
  #pragma unroll
  for (int ni = 0; ni < 2; ++ni) {
    int s = s0 + wn * 64 + ni * 32 + col;
    sc[ni] = s;
    sv[ni] = (s < NP);
    rn[ni] = sv[ni] ? rnormS[s] : 0.f;
  }
  #pragma unroll
  for (int mi = 0; mi < 2; ++mi) {
    #pragma unroll
    for (int reg = 0; reg < 16; ++reg) {
      unsigned long long p = 0ull;
      #pragma unroll
      for (int ni = 0; ni < 2; ++ni) {
        float v = acc[mi][ni][reg] * rn[ni];
        unsigned long long cand =
            ((unsigned long long)ordf(v) << 32) |
            (unsigned long long)(0xFFFFFFFFu - (unsigned)sc[ni]);
        cand = sv[ni] ? cand : 0ull;
        if (cand > p) p = cand;
      }
      #pragma unroll
      for (int sh = 16; sh >= 1; sh >>= 1) {   // reduce within each 32-lane half
        unsigned long long o = __shfl_xor(p, sh, 64);
        if (o > p) p = o;
      }
      int q = q0 + wm * 64 + mi * 32 + (reg & 3) + 8 * (reg >> 2) + 4 * half;
      if (col == 0 && q < NP) atomicMax(best + q, p);
    }
  }
}

// ---------------------------------------------------------------------------
// 4) Final loss: loss = mean_q (synsq[q] - 2*dot + normsq[nn]) / 2304
// ---------------------------------------------------------------------------
__global__ void finalize_kernel(const unsigned long long* __restrict__ best,
                                const float* __restrict__ normS,
                                const float* __restrict__ normsqS,
                                const float* __restrict__ synsq,
                                float* __restrict__ out) {
  __shared__ float sm[256];
  int t = threadIdx.x;
  float accum = 0.f;
  for (int q = t; q < NP; q += 256) {
    unsigned long long p = best[q];
    unsigned int o   = (unsigned int)(p >> 32);
    unsigned int idx = 0xFFFFFFFFu - (unsigned int)(p & 0xFFFFFFFFull);
    unsigned int u   = (o & 0x80000000u) ? (o & 0x7FFFFFFFu) : ~o;
    float resp = __uint_as_float(u);
    float dot  = resp * normS[idx];
    accum += synsq[q] - 2.f * dot + normsqS[idx];
  }
  sm[t] = accum;
  __syncthreads();
  for (int s = 128; s >= 1; s >>= 1) {
    if (t < s) sm[t] += sm[t + s];
    __syncthreads();
  }
  if (t == 0) out[0] = sm[0] / ((float)NP * 2304.f);
}

// ---------------------------------------------------------------------------
extern "C" void kernel_launch(void* const* d_in, const int* in_sizes, int n_in,
                              void* d_out, int out_size, void* d_ws, size_t ws_size,
                              hipStream_t stream) {
  const float* inA = (const float*)d_in[0];  // input  (synthesis)
  const float* inB = (const float*)d_in[1];  // target (style)
  float* out = (float*)d_out;

  char* ws = (char*)d_ws;
  unsigned char* TA = (unsigned char*)ws;                 // 2,359,296 B fp8
  unsigned char* TB = (unsigned char*)(ws + 2359296);     // 2,359,296 B fp8
  float* rnormS  = (float*)(ws + 4718592);
  float* normS   = (float*)(ws + 4718592 + 35344);
  float* normsqS = (float*)(ws + 4718592 + 70688);
  float* synsq   = (float*)(ws + 4718592 + 106032);
  unsigned long long* best = (unsigned long long*)(ws + 4718592 + 141376);

  (void)hipMemsetAsync(best, 0, (size_t)NP * 8, stream);
  prep_kernel<<<dim3(1152), dim3(256), 0, stream>>>(inA, inB, (unsigned int*)TA, (unsigned int*)TB);
  norms_kernel<<<dim3((2 * NP + 3) / 4), dim3(256), 0, stream>>>(
      (const unsigned int*)TA, (const unsigned int*)TB, rnormS, normS, normsqS, synsq);
  gemm_argmax_kernel<<<dim3(NTILE * NTILE), dim3(256), 0, stream>>>(TA, TB, rnormS, best);
  finalize_kernel<<<dim3(1), dim3(256), 0, stream>>>(best, normS, normsqS, synsq, out);
}

// Round 6
// 316.344 us; speedup vs baseline: 1.9344x; 1.1663x over previous
//
#include <hip/hip_runtime.h>
#include <math.h>

// Problem constants
#define NP 8836          // number of patches per image (94*94)
#define PW 94            // patches per row
#define IW 96            // image width/height
#define CH 256           // channels
#define NTILE 70         // ceil(8836/128)
#define KT2 18           // K tiles: 2304/128 (BK=128)

typedef int   i32x4  __attribute__((ext_vector_type(4)));
typedef int   i32x8  __attribute__((ext_vector_type(8)));
typedef float f32x16 __attribute__((ext_vector_type(16)));

__device__ __forceinline__ unsigned int ordf(float f) {
  unsigned int u = __float_as_uint(f);
  return (u & 0x80000000u) ? ~u : (u | 0x80000000u);
}

typedef const __attribute__((address_space(1))) void GvoidC;
typedef __attribute__((address_space(3))) void Lvoid;
__device__ __forceinline__ void gl16(const void* g, void* l) {
  __builtin_amdgcn_global_load_lds((GvoidC*)g, (Lvoid*)l, 16, 0, 0);
}

// ---------------------------------------------------------------------------
// 1) Convert+transpose [C, 9216] fp32 -> [9216, C] fp8 (HW v_cvt encoding).
// ---------------------------------------------------------------------------
__global__ __launch_bounds__(256) void prep_kernel(
    const float* __restrict__ inA, const float* __restrict__ inB,
    unsigned int* __restrict__ TA, unsigned int* __restrict__ TB) {
  __shared__ float tile[64][65];
  int bid = blockIdx.x;            // [0, 1152)
  const float* src; unsigned int* dst;
  if (bid < 576) { src = inA; dst = TA; }
  else           { src = inB; dst = TB; bid -= 576; }
  int cT  = bid & 3;        // c-tile   [0,4)  (64 channels)
  int xyT = bid >> 2;       // xy-tile  [0,144)
  int t = threadIdx.x;
  int l = t & 63, h = t >> 6;

  #pragma unroll
  for (int i = 0; i < 16; ++i) {
    int c = h * 16 + i;
    tile[c][l] = src[(size_t)(cT * 64 + c) * (IW * IW) + xyT * 64 + l];
  }
  __syncthreads();
  int cu = t & 15;          // u32 column within the 64-channel tile
  #pragma unroll
  for (int i = 0; i < 4; ++i) {
    int xy = (t >> 4) + i * 16;
    int c = cu * 4;
    unsigned int v = __builtin_amdgcn_cvt_pk_fp8_f32(tile[c][xy],     tile[c + 1][xy], 0, false);
    v              = __builtin_amdgcn_cvt_pk_fp8_f32(tile[c + 2][xy], tile[c + 3][xy], v, true);
    dst[(size_t)(xyT * 64 + xy) * 64 + cT * 16 + cu] = v;
  }
}

// ---------------------------------------------------------------------------
// 2) Per-patch squared norms from the fp8 images (consistent with GEMM dtype).
// ---------------------------------------------------------------------------
__global__ void norms_kernel(const unsigned int* __restrict__ TA, const unsigned int* __restrict__ TB,
                             float* __restrict__ rnormS, float* __restrict__ normS,
                             float* __restrict__ normsqS, float* __restrict__ synsq) {
  int wid  = blockIdx.x * 4 + (threadIdx.x >> 6);
  int lane = threadIdx.x & 63;
  bool isStyle = wid < NP;
  int p = isStyle ? wid : wid - NP;
  if (p >= NP) return;
  const unsigned int* T = isStyle ? TB : TA;
  int pi = p / PW, pj = p % PW;
  float s = 0.f;
  #pragma unroll
  for (int kh = 0; kh < 3; ++kh) {
    #pragma unroll
    for (int kw = 0; kw < 3; ++kw) {
      unsigned int v = T[(size_t)((pi + kh) * IW + (pj + kw)) * 64 + lane];
      float f0 = __builtin_amdgcn_cvt_f32_fp8(v, 0);
      float f1 = __builtin_amdgcn_cvt_f32_fp8(v, 1);
      float f2 = __builtin_amdgcn_cvt_f32_fp8(v, 2);
      float f3 = __builtin_amdgcn_cvt_f32_fp8(v, 3);
      s += f0 * f0 + f1 * f1 + f2 * f2 + f3 * f3;
    }
  }
  #pragma unroll
  for (int m = 32; m >= 1; m >>= 1) s += __shfl_xor(s, m, 64);
  if (lane == 0) {
    if (isStyle) {
      normsqS[p] = s;
      float n = sqrtf(s);
      normS[p]  = n;
      rnormS[p] = 1.f / n;
    } else {
      synsq[p] = s;
    }
  }
}

// ---------------------------------------------------------------------------
// 3) MX-fp8 implicit-im2col GEMM, 128x128 tile, BK=128 (18 iters, 32 KB LDS),
//    mfma_scale_f32_32x32x64_f8f6f4 x8 per iter, unit scales.
//    LDS row stride = 128 B (32 banks); chunk-XOR swizzle breaks the
//    all-rows-on-one-bank-group pattern: logical 16B chunk q of row r lives
//    at slot q ^ (r&7). Staging fetches global chunk (s ^ (r&7)) into slot s,
//    keeping the wave-uniform-base + lane*16 LDS dest that global_load_lds
//    requires, and 128B-contiguous (permuted) global access per 8 threads.
// ---------------------------------------------------------------------------
__device__ __forceinline__ i32x8 ldfrag(const unsigned char* rowp, int o0, int o1) {
  i32x4 lo = *(const i32x4*)(rowp + o0);
  i32x4 hi = *(const i32x4*)(rowp + o1);
  return __builtin_shufflevector(lo, hi, 0, 1, 2, 3, 4, 5, 6, 7);
}

__global__ __launch_bounds__(256, 2) void gemm_argmax_kernel(
    const unsigned char* __restrict__ TA, const unsigned char* __restrict__ TB,
    const float* __restrict__ rnormS, unsigned long long* __restrict__ best) {
  __shared__ unsigned char As[128 * 128];
  __shared__ unsigned char Bs[128 * 128];

  int pid = blockIdx.x;
  int mt = pid % NTILE, nt = pid / NTILE;
  int q0 = mt * 128, s0 = nt * 128;
  int t = threadIdx.x, lane = t & 63, wave = t >> 6;
  int wm = wave >> 1, wn = wave & 1;

  // Staging: instruction i (0..3) of thread t writes LDS offset i*4096+t*16,
  // i.e. row 32i + (t>>3), slot t&7. It must fetch global chunk
  // qc = (t&7) ^ (row&7) = (t&7) ^ ((t>>3)&7)  (row bits 0-2 are i-invariant).
  int rr = t >> 3;
  int qc = (t & 7) ^ (rr & 7);
  const unsigned char* gA[4];
  const unsigned char* gB[4];
  #pragma unroll
  for (int i = 0; i < 4; ++i) {
    int qa = q0 + 32 * i + rr; if (qa > NP - 1) qa = NP - 1;
    int sa = s0 + 32 * i + rr; if (sa > NP - 1) sa = NP - 1;
    gA[i] = TA + (size_t)((qa / PW) * IW + (qa % PW)) * CH + qc * 16;
    gB[i] = TB + (size_t)((sa / PW) * IW + (sa % PW)) * CH + qc * 16;
  }
  unsigned char* lA = As + t * 16;
  unsigned char* lB = Bs + t * 16;

  f32x16 acc[2][2];
  #pragma unroll
  for (int mi = 0; mi < 2; ++mi)
    #pragma unroll
    for (int ni = 0; ni < 2; ++ni)
      #pragma unroll
      for (int j = 0; j < 16; ++j)
        acc[mi][ni][j] = 0.f;

  // Fragment read bases: row = (wm|wn)*64 + mi*32 + (lane&31), stride 128 B.
  // For k-half h: logical chunks c0 = 2*(lane>>5)+4h, c1 = c0+1;
  // slots = c ^ (lane&7)  (row&7 == lane&7 for all mi/wm offsets).
  int kq = lane >> 5, sw = lane & 7;
  const unsigned char* Arow = As + (size_t)(wm * 64 + (lane & 31)) * 128;
  const unsigned char* Brow = Bs + (size_t)(wn * 64 + (lane & 31)) * 128;

  #pragma unroll 1
  for (int kt = 0; kt < KT2; ++kt) {
    int chunk = kt >> 1;                 // which (kh,kw) of 9
    int kh = chunk / 3, kw = chunk - kh * 3;
    int choff = (kh * IW + kw) * CH + (kt & 1) * 128;   // bytes
    if (kt) __syncthreads();
    #pragma unroll
    for (int i = 0; i < 4; ++i) {
      gl16(gA[i] + choff, lA + i * 4096);
      gl16(gB[i] + choff, lB + i * 4096);
    }
    __syncthreads();

    #pragma unroll
    for (int h = 0; h < 2; ++h) {
      int c0 = 2 * kq + 4 * h;
      int o0 = (c0 ^ sw) * 16, o1 = ((c0 + 1) ^ sw) * 16;
      i32x8 af[2], bf[2];
      #pragma unroll
      for (int mi = 0; mi < 2; ++mi) af[mi] = ldfrag(Arow + mi * 32 * 128, o0, o1);
      #pragma unroll
      for (int ni = 0; ni < 2; ++ni) bf[ni] = ldfrag(Brow + ni * 32 * 128, o0, o1);
      #pragma unroll
      for (int mi = 0; mi < 2; ++mi)
        #pragma unroll
        for (int ni = 0; ni < 2; ++ni)
          acc[mi][ni] = __builtin_amdgcn_mfma_scale_f32_32x32x64_f8f6f4(
              af[mi], bf[ni], acc[mi][ni],
              0, 0,                       // A fmt = fp8(e4m3), B fmt = fp8
              0, 0x7F7F7F7F,              // opsel_a, scale_a = 1.0
              0, 0x7F7F7F7F);             // opsel_b, scale_b = 1.0
    }
  }

  // Epilogue. C/D layout (32x32): col = lane&31, row = (reg&3)+8*(reg>>2)+4*(lane>>5).
  int col = lane & 31, half = lane >> 5;
  float rn[2]; int sc[2]; bool sv[2];
  #pragma unroll
  for (int ni = 0; ni < 2; ++ni) {
    int s = s0 + wn * 64 + ni * 32 + col;
    sc[ni] = s;
    sv[ni] = (s < NP);
    rn[ni] = sv[ni] ? rnormS[s] : 0.f;
  }
  #pragma unroll
  for (int mi = 0; mi < 2; ++mi) {
    #pragma unroll
    for (int reg = 0; reg < 16; ++reg) {
      unsigned long long p = 0ull;
      #pragma unroll
      for (int ni = 0; ni < 2; ++ni) {
        float v = acc[mi][ni][reg] * rn[ni];
        unsigned long long cand =
            ((unsigned long long)ordf(v) << 32) |
            (unsigned long long)(0xFFFFFFFFu - (unsigned)sc[ni]);
        cand = sv[ni] ? cand : 0ull;
        if (cand > p) p = cand;
      }
      #pragma unroll
      for (int sh = 16; sh >= 1; sh >>= 1) {   // reduce within each 32-lane half
        unsigned long long o = __shfl_xor(p, sh, 64);
        if (o > p) p = o;
      }
      int q = q0 + wm * 64 + mi * 32 + (reg & 3) + 8 * (reg >> 2) + 4 * half;
      if (col == 0 && q < NP) atomicMax(best + q, p);
    }
  }
}

// ---------------------------------------------------------------------------
// 4) Final loss: loss = mean_q (synsq[q] - 2*dot + normsq[nn]) / 2304
// ---------------------------------------------------------------------------
__global__ void finalize_kernel(const unsigned long long* __restrict__ best,
                                const float* __restrict__ normS,
                                const float* __restrict__ normsqS,
                                const float* __restrict__ synsq,
                                float* __restrict__ out) {
  __shared__ float sm[256];
  int t = threadIdx.x;
  float accum = 0.f;
  for (int q = t; q < NP; q += 256) {
    unsigned long long p = best[q];
    unsigned int o   = (unsigned int)(p >> 32);
    unsigned int idx = 0xFFFFFFFFu - (unsigned int)(p & 0xFFFFFFFFull);
    unsigned int u   = (o & 0x80000000u) ? (o & 0x7FFFFFFFu) : ~o;
    float resp = __uint_as_float(u);
    float dot  = resp * normS[idx];
    accum += synsq[q] - 2.f * dot + normsqS[idx];
  }
  sm[t] = accum;
  __syncthreads();
  for (int s = 128; s >= 1; s >>= 1) {
    if (t < s) sm[t] += sm[t + s];
    __syncthreads();
  }
  if (t == 0) out[0] = sm[0] / ((float)NP * 2304.f);
}

// ---------------------------------------------------------------------------
extern "C" void kernel_launch(void* const* d_in, const int* in_sizes, int n_in,
                              void* d_out, int out_size, void* d_ws, size_t ws_size,
                              hipStream_t stream) {
  const float* inA = (const float*)d_in[0];  // input  (synthesis)
  const float* inB = (const float*)d_in[1];  // target (style)
  float* out = (float*)d_out;

  char* ws = (char*)d_ws;
  unsigned char* TA = (unsigned char*)ws;                 // 2,359,296 B fp8
  unsigned char* TB = (unsigned char*)(ws + 2359296);     // 2,359,296 B fp8
  float* rnormS  = (float*)(ws + 4718592);
  float* normS   = (float*)(ws + 4718592 + 35344);
  float* normsqS = (float*)(ws + 4718592 + 70688);
  float* synsq   = (float*)(ws + 4718592 + 106032);
  unsigned long long* best = (unsigned long long*)(ws + 4718592 + 141376);

  (void)hipMemsetAsync(best, 0, (size_t)NP * 8, stream);
  prep_kernel<<<dim3(1152), dim3(256), 0, stream>>>(inA, inB, (unsigned int*)TA, (unsigned int*)TB);
  norms_kernel<<<dim3((2 * NP + 3) / 4), dim3(256), 0, stream>>>(
      (const unsigned int*)TA, (const unsigned int*)TB, rnormS, normS, normsqS, synsq);
  gemm_argmax_kernel<<<dim3(NTILE * NTILE), dim3(256), 0, stream>>>(TA, TB, rnormS, best);
  finalize_kernel<<<dim3(1), dim3(256), 0, stream>>>(best, normS, normsqS, synsq, out);
}